// Round 1
// baseline (500.345 us; speedup 1.0000x reference)
//
#include <hip/hip_runtime.h>

typedef _Float16 f16x8 __attribute__((ext_vector_type(8)));
typedef _Float16 f16x4 __attribute__((ext_vector_type(4)));
typedef float f32x4 __attribute__((ext_vector_type(4)));

#define DEVI __device__ __forceinline__

constexpr int NROWS = 2048;
constexpr int HEADP = 20096;   // 157*128 (20002 padded)
constexpr int NCB_H = 157;
constexpr int PST_H = 160;
constexpr int VT    = 40000;
constexpr int VTP   = 40064;   // 313*128
constexpr int NCB_T = 313;
constexpr int PST_T = 320;

DEVI void glds16(const void* g, void* l) {
  __builtin_amdgcn_global_load_lds((const __attribute__((address_space(1))) unsigned int*)g,
                                   (__attribute__((address_space(3))) unsigned int*)l,
                                   16, 0, 0);
}

// ---------------- prep: per-row label info + compaction lists ----------------
__global__ void prep_kernel(const int* __restrict__ x, const int* __restrict__ labels,
                            int* cl, int* headcol, int* tailpos, int* pos1, int* pos2,
                            int* L1, int* L2, int* T0, int* T1, int* T2, int* counts)
{
  __shared__ int sc[3][256];
  int tid = threadIdx.x;
  int base = tid * 8;
  // ---- phase A: labels ----
  int lcl[8]; int c1 = 0, c2 = 0;
  for (int j = 0; j < 8; j++) {
    int l = labels[base + j];
    int c = l < 20000 ? 0 : (l < 60000 ? 1 : 2);
    lcl[j] = c;
    cl[base + j] = c;
    headcol[base + j] = c == 0 ? l : (c == 1 ? 20001 : 20000);
    tailpos[base + j] = c == 1 ? l - 20000 : (c == 2 ? l - 60000 : 0);
    if (c == 1) c1++; else if (c == 2) c2++;
  }
  sc[1][tid] = c1; sc[2][tid] = c2;
  __syncthreads();
  for (int d = 1; d < 256; d <<= 1) {
    int v1 = tid >= d ? sc[1][tid - d] : 0;
    int v2 = tid >= d ? sc[2][tid - d] : 0;
    __syncthreads();
    sc[1][tid] += v1; sc[2][tid] += v2;
    __syncthreads();
  }
  int o1 = sc[1][tid] - c1, o2 = sc[2][tid] - c2;
  int cnt1 = sc[1][255], cnt2 = sc[2][255];
  for (int j = 0; j < 8; j++) {
    int n = base + j; int c = lcl[j];
    if (c == 1)      { pos1[n] = o1; L1[o1] = n; o1++; pos2[n] = 0; }
    else if (c == 2) { pos2[n] = o2; L2[o2] = n; o2++; pos1[n] = 0; }
    else             { pos1[n] = 0; pos2[n] = 0; }
  }
  for (int i = cnt1 + tid; i < NROWS; i += 256) L1[i] = 0;
  for (int i = cnt2 + tid; i < NROWS; i += 256) L2[i] = 0;
  if (tid == 0) { counts[0] = cnt1; counts[1] = cnt2; }
  __syncthreads();
  // ---- phase B: tokens ----
  int tcl[8]; int t0 = 0, t1 = 0, t2 = 0;
  for (int j = 0; j < 8; j++) {
    int t = x[base + j];
    int c = t < 20000 ? 0 : (t < 60000 ? 1 : 2);
    tcl[j] = c;
    if (c == 0) t0++; else if (c == 1) t1++; else t2++;
  }
  sc[0][tid] = t0; sc[1][tid] = t1; sc[2][tid] = t2;
  __syncthreads();
  for (int d = 1; d < 256; d <<= 1) {
    int v0 = tid >= d ? sc[0][tid - d] : 0;
    int v1 = tid >= d ? sc[1][tid - d] : 0;
    int v2 = tid >= d ? sc[2][tid - d] : 0;
    __syncthreads();
    sc[0][tid] += v0; sc[1][tid] += v1; sc[2][tid] += v2;
    __syncthreads();
  }
  int q0 = sc[0][tid] - t0, q1 = sc[1][tid] - t1, q2 = sc[2][tid] - t2;
  int tc0 = sc[0][255], tc1 = sc[1][255], tc2 = sc[2][255];
  for (int j = 0; j < 8; j++) {
    int n = base + j; int c = tcl[j];
    if (c == 0) T0[q0++] = n;
    else if (c == 1) T1[q1++] = n;
    else T2[q2++] = n;
  }
  for (int i = tc0 + tid; i < NROWS; i += 256) T0[i] = 0;
  for (int i = tc1 + tid; i < NROWS; i += 256) T1[i] = 0;
  for (int i = tc2 + tid; i < NROWS; i += 256) T2[i] = 0;
  if (tid == 0) { counts[2] = tc0; counts[3] = tc1; counts[4] = tc2; }
}

// ---------------- weight packing / conversion ----------------
__global__ void pack_headw(const float* __restrict__ w0, const float* __restrict__ b0,
                           const float* __restrict__ cw, const float* __restrict__ cb,
                           _Float16* __restrict__ dstW, float* __restrict__ dstB)
{
  int g = blockIdx.x * 256 + threadIdx.x;       // over HEADP*1024/4
  int r = g >> 8;
  int k4 = (g & 255) << 2;
  float4 v;
  if (r < 20000)      v = *(const float4*)(w0 + ((size_t)r << 10) + k4);
  else if (r < 20002) v = *(const float4*)(cw + ((size_t)(r - 20000) << 10) + k4);
  else                v = make_float4(0.f, 0.f, 0.f, 0.f);
  f16x4 o = {(_Float16)v.x, (_Float16)v.y, (_Float16)v.z, (_Float16)v.w};
  *(f16x4*)(dstW + ((size_t)r << 10) + k4) = o;
  if (g < HEADP) dstB[g] = g < 20000 ? b0[g] : (g < 20002 ? cb[g - 20000] : -1e30f);
}

__global__ void pack_tail(const float* __restrict__ w, const float* __restrict__ b,
                          _Float16* __restrict__ dstW, float* __restrict__ dstB, int log2E)
{
  int g = blockIdx.x * 256 + threadIdx.x;       // over VTP*E/4
  int r = g >> (log2E - 2);
  int k4 = (g & ((1 << (log2E - 2)) - 1)) << 2;
  float4 v = r < VT ? *(const float4*)(w + ((size_t)r << log2E) + k4)
                    : make_float4(0.f, 0.f, 0.f, 0.f);
  f16x4 o = {(_Float16)v.x, (_Float16)v.y, (_Float16)v.z, (_Float16)v.w};
  *(f16x4*)(dstW + ((size_t)r << log2E) + k4) = o;
  if (g < VTP) dstB[g] = g < VT ? b[g] : -1e30f;
}

__global__ void convert_f16(const float* __restrict__ src, _Float16* __restrict__ dst, int total4)
{
  int g = blockIdx.x * 256 + threadIdx.x;
  if (g >= total4) return;
  float4 v = *(const float4*)(src + (size_t)g * 4);
  f16x4 o = {(_Float16)v.x, (_Float16)v.y, (_Float16)v.z, (_Float16)v.w};
  *(f16x4*)(dst + (size_t)g * 4) = o;
}

// out[c][r] = in[r][c]  (f32 -> f16), rows of out beyond C zero-padded to Cpad
__global__ void transpose_f16(const float* __restrict__ in, _Float16* __restrict__ out,
                              int R, int C)
{
  __shared__ float tile[32][33];
  int c0 = blockIdx.x * 32, r0 = blockIdx.y * 32;
  int tx = threadIdx.x, ty = threadIdx.y;       // (32, 8)
  for (int i = 0; i < 4; i++) {
    int c = c0 + tx; int r = r0 + ty + i * 8;
    tile[ty + i * 8][tx] = (c < C) ? in[(size_t)r * C + c] : 0.f;
  }
  __syncthreads();
  for (int i = 0; i < 4; i++)
    out[(size_t)(c0 + ty + i * 8) * R + r0 + tx] = (_Float16)tile[tx][ty + i * 8];
}

// gather emb rows (by token list), *32 scale, -> f16 compact matrix
__global__ void gather_emb(const float* __restrict__ emb, const int* __restrict__ x,
                           const int* __restrict__ list, _Float16* __restrict__ dst,
                           int tbase, int vmax, int log2E, int total4)
{
  int g = blockIdx.x * 256 + threadIdx.x;
  if (g >= total4) return;
  int r = g >> (log2E - 2);
  int e4 = (g & ((1 << (log2E - 2)) - 1)) << 2;
  int n = list[r];
  int tl = x[n] - tbase;
  tl = tl < 0 ? 0 : (tl >= vmax ? vmax - 1 : tl);
  float4 v = *(const float4*)(emb + ((size_t)tl << log2E) + e4);
  f16x4 o = {(_Float16)(v.x * 32.f), (_Float16)(v.y * 32.f),
             (_Float16)(v.z * 32.f), (_Float16)(v.w * 32.f)};
  *(f16x4*)(dst + ((size_t)r << log2E) + e4) = o;
}

// ---------------- core GEMM: C[m][n] = sum_k A[m][k] * W[n][k] ----------------
// EPI=0: store C as f16 (optional row scatter via cmap, row mask via cnt, col mask Nvalid)
// EPI=1: add bias, per-row online-LSE partials (max, sumexp) per 128-col block
template<int EPI>
__global__ __launch_bounds__(256)
void gemm_f16(const _Float16* __restrict__ A, int lda,
              const _Float16* __restrict__ Wm, int ldw,
              const float* __restrict__ bias,
              _Float16* __restrict__ C, int ldc, int Nvalid,
              const int* __restrict__ amap,
              const int* __restrict__ cmap,
              const int* __restrict__ cnt,
              float* __restrict__ pm, float* __restrict__ ps, int pstride,
              int K)
{
  int rb = blockIdx.x, cb = blockIdx.y;
  int valid = cnt ? *cnt : NROWS;
  if (cnt && rb * 128 >= valid) return;
  __shared__ __attribute__((aligned(16))) _Float16 As[128 * 32];
  __shared__ __attribute__((aligned(16))) _Float16 Ws[128 * 32];
  __shared__ float lmax[2][128], lsum[2][128];
  int tid = threadIdx.x;
  int lane = tid & 63, wid = tid >> 6;
  int wr = wid >> 1, wc = wid & 1;
  // staging addresses: wave wid owns tile rows [wid*32, wid*32+32)
  int sr = wid * 32 + (lane >> 2);
  int arow0 = rb * 128 + sr, arow1 = arow0 + 16;
  if (amap) { arow0 = amap[arow0]; arow1 = amap[arow1]; }
  int ko = (lane & 3) * 8;
  const _Float16* ag0 = A + (size_t)arow0 * lda + ko;
  const _Float16* ag1 = A + (size_t)arow1 * lda + ko;
  const _Float16* wg0 = Wm + (size_t)(cb * 128 + sr) * ldw + ko;
  const _Float16* wg1 = wg0 + (size_t)16 * ldw;
  _Float16* as0 = As + (wid * 32) * 32;
  _Float16* as1 = as0 + 16 * 32;
  _Float16* ws0 = Ws + (wid * 32) * 32;
  _Float16* ws1 = ws0 + 16 * 32;
  f32x4 acc[4][4] = {};
  int lr = lane & 15, lk = (lane >> 4) * 8;
  const int nk = K >> 5;
  for (int kt = 0; kt < nk; ++kt) {
    int kofs = kt * 32;
    glds16(ag0 + kofs, as0);
    glds16(ag1 + kofs, as1);
    glds16(wg0 + kofs, ws0);
    glds16(wg1 + kofs, ws1);
    __syncthreads();            // compiler drains vmcnt before barrier
    f16x8 af[4], bf[4];
    #pragma unroll
    for (int mi = 0; mi < 4; mi++)
      af[mi] = *(const f16x8*)(As + (wr * 64 + mi * 16 + lr) * 32 + lk);
    #pragma unroll
    for (int ni = 0; ni < 4; ni++)
      bf[ni] = *(const f16x8*)(Ws + (wc * 64 + ni * 16 + lr) * 32 + lk);
    #pragma unroll
    for (int mi = 0; mi < 4; mi++)
      #pragma unroll
      for (int ni = 0; ni < 4; ni++)
        acc[mi][ni] = __builtin_amdgcn_mfma_f32_16x16x32_f16(af[mi], bf[ni], acc[mi][ni], 0, 0, 0);
    __syncthreads();
  }
  if (EPI == 0) {
    #pragma unroll
    for (int mi = 0; mi < 4; mi++) {
      #pragma unroll
      for (int j = 0; j < 4; j++) {
        int rl = wr * 64 + mi * 16 + (lane >> 4) * 4 + j;
        int rg = rb * 128 + rl;
        if (rg >= valid) continue;
        int orow = cmap ? cmap[rg] : rg;
        #pragma unroll
        for (int ni = 0; ni < 4; ni++) {
          int col = cb * 128 + wc * 64 + ni * 16 + (lane & 15);
          if (col < Nvalid) C[(size_t)orow * ldc + col] = (_Float16)acc[mi][ni][j];
        }
      }
    }
  } else {
    float bv[4];
    #pragma unroll
    for (int ni = 0; ni < 4; ni++)
      bv[ni] = bias[cb * 128 + wc * 64 + ni * 16 + (lane & 15)];
    #pragma unroll
    for (int mi = 0; mi < 4; mi++) {
      #pragma unroll
      for (int j = 0; j < 4; j++) {
        float v0 = acc[mi][0][j] + bv[0], v1 = acc[mi][1][j] + bv[1];
        float v2 = acc[mi][2][j] + bv[2], v3 = acc[mi][3][j] + bv[3];
        float m = fmaxf(fmaxf(v0, v1), fmaxf(v2, v3));
        #pragma unroll
        for (int d = 1; d < 16; d <<= 1) m = fmaxf(m, __shfl_xor(m, d));
        float s = __expf(v0 - m) + __expf(v1 - m) + __expf(v2 - m) + __expf(v3 - m);
        #pragma unroll
        for (int d = 1; d < 16; d <<= 1) s += __shfl_xor(s, d);
        if ((lane & 15) == 0) {
          int rl = wr * 64 + mi * 16 + (lane >> 4) * 4 + j;
          lmax[wc][rl] = m; lsum[wc][rl] = s;
        }
      }
    }
    __syncthreads();
    if (tid < 128) {
      float m0 = lmax[0][tid], m1 = lmax[1][tid];
      float M = fmaxf(m0, m1);
      float S = lsum[0][tid] * __expf(m0 - M) + lsum[1][tid] * __expf(m1 - M);
      int rg = rb * 128 + tid;
      pm[(size_t)rg * pstride + cb] = M;
      ps[(size_t)rg * pstride + cb] = S;
    }
  }
}

// ---------------- per-row target logits ----------------
__global__ void target_kernel(const _Float16* __restrict__ ph0, const _Float16* __restrict__ headw,
                              const float* __restrict__ headb,
                              const _Float16* __restrict__ ph1c, const _Float16* __restrict__ w1p,
                              const float* __restrict__ b1p,
                              const _Float16* __restrict__ ph2c, const _Float16* __restrict__ w2p,
                              const float* __restrict__ b2p,
                              const int* __restrict__ headcol, const int* __restrict__ tailpos,
                              const int* __restrict__ pos1, const int* __restrict__ pos2,
                              float* __restrict__ tl)
{
  int n = blockIdx.x;
  int tid = threadIdx.x, lane = tid & 63, wid = tid >> 6;
  if (wid == 0) {
    int c = headcol[n];
    const f16x8* a = (const f16x8*)(ph0 + (size_t)n * 1024 + lane * 16);
    const f16x8* w = (const f16x8*)(headw + (size_t)c * 1024 + lane * 16);
    float s = 0.f;
    #pragma unroll
    for (int u = 0; u < 2; u++) {
      f16x8 av = a[u], wv = w[u];
      #pragma unroll
      for (int j = 0; j < 8; j++) s += (float)av[j] * (float)wv[j];
    }
    for (int d = 1; d < 64; d <<= 1) s += __shfl_xor(s, d);
    if (lane == 0) tl[n * 4 + 0] = s + headb[c];
  } else if (wid == 1) {
    int c = tailpos[n];
    f16x4 av = *(const f16x4*)(ph1c + (size_t)pos1[n] * 256 + lane * 4);
    f16x4 wv = *(const f16x4*)(w1p + (size_t)c * 256 + lane * 4);
    float s = (float)av[0] * (float)wv[0] + (float)av[1] * (float)wv[1]
            + (float)av[2] * (float)wv[2] + (float)av[3] * (float)wv[3];
    for (int d = 1; d < 64; d <<= 1) s += __shfl_xor(s, d);
    if (lane == 0) tl[n * 4 + 1] = s + b1p[c];
  } else if (wid == 2) {
    int c = tailpos[n];
    float s = (float)ph2c[(size_t)pos2[n] * 64 + lane] * (float)w2p[(size_t)c * 64 + lane];
    for (int d = 1; d < 64; d <<= 1) s += __shfl_xor(s, d);
    if (lane == 0) tl[n * 4 + 2] = s + b2p[c];
  }
}

// ---------------- reduce partials -> LSE -> NLL ----------------
__global__ void reduce_kernel(const float* __restrict__ pmh, const float* __restrict__ psh,
                              const float* __restrict__ pm1, const float* __restrict__ ps1,
                              const float* __restrict__ pm2, const float* __restrict__ ps2,
                              const int* __restrict__ cl, const int* __restrict__ pos1,
                              const int* __restrict__ pos2,
                              const float* __restrict__ tl, float* __restrict__ out)
{
  int n = blockIdx.x;
  int tid = threadIdx.x, lane = tid & 63, wid = tid >> 6;
  __shared__ float lse[3];
  if (wid == 0) {
    const float* m = pmh + (size_t)n * PST_H;
    const float* s = psh + (size_t)n * PST_H;
    float M = -3e38f;
    for (int i = lane; i < NCB_H; i += 64) M = fmaxf(M, m[i]);
    for (int d = 1; d < 64; d <<= 1) M = fmaxf(M, __shfl_xor(M, d));
    float S = 0.f;
    for (int i = lane; i < NCB_H; i += 64) S += s[i] * __expf(m[i] - M);
    for (int d = 1; d < 64; d <<= 1) S += __shfl_xor(S, d);
    if (lane == 0) lse[0] = M + __logf(S);
  } else if (wid == 1) {
    const float* m = pm1 + (size_t)pos1[n] * PST_T;
    const float* s = ps1 + (size_t)pos1[n] * PST_T;
    float M = -3e38f;
    for (int i = lane; i < NCB_T; i += 64) M = fmaxf(M, m[i]);
    for (int d = 1; d < 64; d <<= 1) M = fmaxf(M, __shfl_xor(M, d));
    float S = 0.f;
    for (int i = lane; i < NCB_T; i += 64) S += s[i] * __expf(m[i] - M);
    for (int d = 1; d < 64; d <<= 1) S += __shfl_xor(S, d);
    if (lane == 0) lse[1] = M + __logf(S);
  } else if (wid == 2) {
    const float* m = pm2 + (size_t)pos2[n] * PST_T;
    const float* s = ps2 + (size_t)pos2[n] * PST_T;
    float M = -3e38f;
    for (int i = lane; i < NCB_T; i += 64) M = fmaxf(M, m[i]);
    for (int d = 1; d < 64; d <<= 1) M = fmaxf(M, __shfl_xor(M, d));
    float S = 0.f;
    for (int i = lane; i < NCB_T; i += 64) S += s[i] * __expf(m[i] - M);
    for (int d = 1; d < 64; d <<= 1) S += __shfl_xor(S, d);
    if (lane == 0) lse[2] = M + __logf(S);
  }
  __syncthreads();
  if (tid == 0) {
    int c = cl[n];
    float nll = lse[0] - tl[n * 4 + 0];
    if (c == 1)      nll += lse[1] - tl[n * 4 + 1];
    else if (c == 2) nll += lse[2] - tl[n * 4 + 2];
    out[n] = nll;
  }
}

// ---------------- driver ----------------
extern "C" void kernel_launch(void* const* d_in, const int* in_sizes, int n_in,
                              void* d_out, int out_size, void* d_ws, size_t ws_size,
                              hipStream_t stream)
{
  const int*   x         = (const int*)d_in[0];
  const int*   labels    = (const int*)d_in[1];
  const float* emb_w0    = (const float*)d_in[2];
  const float* emb_w1    = (const float*)d_in[3];
  const float* emb_w2    = (const float*)d_in[4];
  const float* emb_proj0 = (const float*)d_in[5];
  const float* emb_proj1 = (const float*)d_in[6];
  const float* emb_proj2 = (const float*)d_in[7];
  const float* out_w0    = (const float*)d_in[8];
  const float* out_b0    = (const float*)d_in[9];
  const float* out_w1    = (const float*)d_in[10];
  const float* out_b1    = (const float*)d_in[11];
  const float* out_w2    = (const float*)d_in[12];
  const float* out_b2    = (const float*)d_in[13];
  const float* out_proj0 = (const float*)d_in[14];
  const float* out_proj1 = (const float*)d_in[15];
  const float* out_proj2 = (const float*)d_in[16];
  const float* cluster_w = (const float*)d_in[17];
  const float* cluster_b = (const float*)d_in[18];
  float* out = (float*)d_out;

  char* ws = (char*)d_ws;
  size_t off = 0;
  auto alloc = [&](size_t bytes) -> void* {
    void* p = ws + off;
    off = (off + bytes + 255) & ~(size_t)255;
    return p;
  };
  _Float16* headw = (_Float16*)alloc((size_t)HEADP * 1024 * 2);
  float*    headb = (float*)alloc((size_t)HEADP * 4);
  _Float16* w1p   = (_Float16*)alloc((size_t)VTP * 256 * 2);
  float*    b1p   = (float*)alloc((size_t)VTP * 4);
  _Float16* w2p   = (_Float16*)alloc((size_t)VTP * 64 * 2);
  float*    b2p   = (float*)alloc((size_t)VTP * 4);
  _Float16* ep0f  = (_Float16*)alloc((size_t)1024 * 1024 * 2);
  _Float16* ep1f  = (_Float16*)alloc((size_t)1024 * 256 * 2);
  _Float16* ep2f  = (_Float16*)alloc((size_t)1024 * 64 * 2);
  _Float16* op0T  = (_Float16*)alloc((size_t)1024 * 1024 * 2);
  _Float16* op1T  = (_Float16*)alloc((size_t)256 * 1024 * 2);
  _Float16* op2T  = (_Float16*)alloc((size_t)128 * 1024 * 2);
  _Float16* E0    = (_Float16*)alloc((size_t)NROWS * 1024 * 2);
  _Float16* E1    = (_Float16*)alloc((size_t)NROWS * 256 * 2);
  _Float16* E2    = (_Float16*)alloc((size_t)NROWS * 64 * 2);
  _Float16* hid   = (_Float16*)alloc((size_t)NROWS * 1024 * 2);
  _Float16* ph0   = (_Float16*)alloc((size_t)NROWS * 1024 * 2);
  _Float16* ph1c  = (_Float16*)alloc((size_t)NROWS * 256 * 2);
  _Float16* ph2c  = (_Float16*)alloc((size_t)NROWS * 64 * 2);
  float* pmh = (float*)alloc((size_t)NROWS * PST_H * 4);
  float* psh = (float*)alloc((size_t)NROWS * PST_H * 4);
  float* pm1 = (float*)alloc((size_t)NROWS * PST_T * 4);
  float* ps1 = (float*)alloc((size_t)NROWS * PST_T * 4);
  float* pm2 = (float*)alloc((size_t)NROWS * PST_T * 4);
  float* ps2 = (float*)alloc((size_t)NROWS * PST_T * 4);
  int* L1 = (int*)alloc(NROWS * 4);
  int* L2 = (int*)alloc(NROWS * 4);
  int* T0 = (int*)alloc(NROWS * 4);
  int* T1 = (int*)alloc(NROWS * 4);
  int* T2 = (int*)alloc(NROWS * 4);
  int* counts  = (int*)alloc(16 * 4);
  int* cl      = (int*)alloc(NROWS * 4);
  int* headcol = (int*)alloc(NROWS * 4);
  int* tailpos = (int*)alloc(NROWS * 4);
  int* pos1    = (int*)alloc(NROWS * 4);
  int* pos2    = (int*)alloc(NROWS * 4);
  float* tl    = (float*)alloc(NROWS * 4 * 4);
  (void)ws_size; (void)in_sizes; (void)n_in; (void)out_size;

  prep_kernel<<<1, 256, 0, stream>>>(x, labels, cl, headcol, tailpos, pos1, pos2,
                                     L1, L2, T0, T1, T2, counts);

  pack_headw<<<HEADP * 1024 / 4 / 256, 256, 0, stream>>>(out_w0, out_b0, cluster_w, cluster_b,
                                                          headw, headb);
  pack_tail<<<VTP * 256 / 4 / 256, 256, 0, stream>>>(out_w1, out_b1, w1p, b1p, 8);
  pack_tail<<<VTP * 64 / 4 / 256, 256, 0, stream>>>(out_w2, out_b2, w2p, b2p, 6);
  convert_f16<<<1024 * 1024 / 4 / 256, 256, 0, stream>>>(emb_proj0, ep0f, 1024 * 1024 / 4);
  convert_f16<<<1024 * 256 / 4 / 256, 256, 0, stream>>>(emb_proj1, ep1f, 1024 * 256 / 4);
  convert_f16<<<1024 * 64 / 4 / 256, 256, 0, stream>>>(emb_proj2, ep2f, 1024 * 64 / 4);
  transpose_f16<<<dim3(32, 32), dim3(32, 8), 0, stream>>>(out_proj0, op0T, 1024, 1024);
  transpose_f16<<<dim3(8, 32), dim3(32, 8), 0, stream>>>(out_proj1, op1T, 1024, 256);
  transpose_f16<<<dim3(4, 32), dim3(32, 8), 0, stream>>>(out_proj2, op2T, 1024, 64);
  gather_emb<<<NROWS * 1024 / 4 / 256, 256, 0, stream>>>(emb_w0, x, T0, E0, 0, 20000, 10,
                                                          NROWS * 1024 / 4);
  gather_emb<<<NROWS * 256 / 4 / 256, 256, 0, stream>>>(emb_w1, x, T1, E1, 20000, 40000, 8,
                                                         NROWS * 256 / 4);
  gather_emb<<<NROWS * 64 / 4 / 256, 256, 0, stream>>>(emb_w2, x, T2, E2, 60000, 40000, 6,
                                                        NROWS * 64 / 4);

  // hidden per token cluster: hid[orig_row] = E_c @ eproj_c^T (scatter via T-lists)
  gemm_f16<0><<<dim3(16, 8), 256, 0, stream>>>(E0, 1024, ep0f, 1024, nullptr,
      hid, 1024, 1024, nullptr, T0, counts + 2, nullptr, nullptr, 0, 1024);
  gemm_f16<0><<<dim3(16, 8), 256, 0, stream>>>(E1, 256, ep1f, 256, nullptr,
      hid, 1024, 1024, nullptr, T1, counts + 3, nullptr, nullptr, 0, 256);
  gemm_f16<0><<<dim3(16, 8), 256, 0, stream>>>(E2, 64, ep2f, 64, nullptr,
      hid, 1024, 1024, nullptr, T2, counts + 4, nullptr, nullptr, 0, 64);

  // projections
  gemm_f16<0><<<dim3(16, 8), 256, 0, stream>>>(hid, 1024, op0T, 1024, nullptr,
      ph0, 1024, 1024, nullptr, nullptr, nullptr, nullptr, nullptr, 0, 1024);
  gemm_f16<0><<<dim3(16, 2), 256, 0, stream>>>(hid, 1024, op1T, 1024, nullptr,
      ph1c, 256, 256, L1, nullptr, counts + 0, nullptr, nullptr, 0, 1024);
  gemm_f16<0><<<dim3(16, 1), 256, 0, stream>>>(hid, 1024, op2T, 1024, nullptr,
      ph2c, 64, 64, L2, nullptr, counts + 1, nullptr, nullptr, 0, 1024);

  // logits + online-LSE partials
  gemm_f16<1><<<dim3(16, NCB_H), 256, 0, stream>>>(ph0, 1024, headw, 1024, headb,
      nullptr, 0, 0, nullptr, nullptr, nullptr, pmh, psh, PST_H, 1024);
  gemm_f16<1><<<dim3(16, NCB_T), 256, 0, stream>>>(ph1c, 256, w1p, 256, b1p,
      nullptr, 0, 0, nullptr, nullptr, counts + 0, pm1, ps1, PST_T, 256);
  gemm_f16<1><<<dim3(16, NCB_T), 256, 0, stream>>>(ph2c, 64, w2p, 64, b2p,
      nullptr, 0, 0, nullptr, nullptr, counts + 1, pm2, ps2, PST_T, 64);

  target_kernel<<<NROWS, 192, 0, stream>>>(ph0, headw, headb, ph1c, w1p, b1p,
                                           ph2c, w2p, b2p, headcol, tailpos, pos1, pos2, tl);
  reduce_kernel<<<NROWS, 192, 0, stream>>>(pmh, psh, pm1, ps1, pm2, ps2,
                                           cl, pos1, pos2, tl, out);
}

// Round 2
// 409.084 us; speedup vs baseline: 1.2231x; 1.2231x over previous
//
#include <hip/hip_runtime.h>
#include <type_traits>

typedef _Float16 f16x8 __attribute__((ext_vector_type(8)));
typedef _Float16 f16x4 __attribute__((ext_vector_type(4)));
typedef float f32x4 __attribute__((ext_vector_type(4)));

#define DEVI __device__ __forceinline__

constexpr int NROWS = 2048;
constexpr int HEADP = 20224;   // 79*256 (20002 padded)
constexpr int NCBH  = 79;
constexpr int PSTH  = 80;
constexpr int VT    = 40000;
constexpr int VTP   = 40192;   // 157*256
constexpr int NCBT  = 157;
constexpr int PSTT  = 160;

DEVI void glds16(const void* g, void* l) {
  __builtin_amdgcn_global_load_lds((const __attribute__((address_space(1))) unsigned int*)g,
                                   (__attribute__((address_space(3))) unsigned int*)l,
                                   16, 0, 0);
}

#define VMW(N) asm volatile("s_waitcnt vmcnt(" #N ")" ::: "memory")
#define BARX do { __builtin_amdgcn_s_barrier(); __builtin_amdgcn_sched_barrier(0); } while (0)
#define PR1 __builtin_amdgcn_s_setprio(1)
#define PR0 __builtin_amdgcn_s_setprio(0)

// ---------------- prep: per-row label info + compaction lists ----------------
__global__ void prep_kernel(const int* __restrict__ x, const int* __restrict__ labels,
                            int* cl, int* headcol, int* tailpos, int* pos1, int* pos2,
                            int* L1, int* L2, int* T0, int* T1, int* T2, int* counts)
{
  __shared__ int sc[3][256];
  int tid = threadIdx.x;
  int base = tid * 8;
  int lcl[8]; int c1 = 0, c2 = 0;
  for (int j = 0; j < 8; j++) {
    int l = labels[base + j];
    int c = l < 20000 ? 0 : (l < 60000 ? 1 : 2);
    lcl[j] = c;
    cl[base + j] = c;
    headcol[base + j] = c == 0 ? l : (c == 1 ? 20001 : 20000);
    tailpos[base + j] = c == 1 ? l - 20000 : (c == 2 ? l - 60000 : 0);
    if (c == 1) c1++; else if (c == 2) c2++;
  }
  sc[1][tid] = c1; sc[2][tid] = c2;
  __syncthreads();
  for (int d = 1; d < 256; d <<= 1) {
    int v1 = tid >= d ? sc[1][tid - d] : 0;
    int v2 = tid >= d ? sc[2][tid - d] : 0;
    __syncthreads();
    sc[1][tid] += v1; sc[2][tid] += v2;
    __syncthreads();
  }
  int o1 = sc[1][tid] - c1, o2 = sc[2][tid] - c2;
  int cnt1 = sc[1][255], cnt2 = sc[2][255];
  for (int j = 0; j < 8; j++) {
    int n = base + j; int c = lcl[j];
    if (c == 1)      { pos1[n] = o1; L1[o1] = n; o1++; pos2[n] = 0; }
    else if (c == 2) { pos2[n] = o2; L2[o2] = n; o2++; pos1[n] = 0; }
    else             { pos1[n] = 0; pos2[n] = 0; }
  }
  for (int i = cnt1 + tid; i < NROWS; i += 256) L1[i] = 0;
  for (int i = cnt2 + tid; i < NROWS; i += 256) L2[i] = 0;
  if (tid == 0) { counts[0] = cnt1; counts[1] = cnt2; }
  __syncthreads();
  int tcl[8]; int t0 = 0, t1 = 0, t2 = 0;
  for (int j = 0; j < 8; j++) {
    int t = x[base + j];
    int c = t < 20000 ? 0 : (t < 60000 ? 1 : 2);
    tcl[j] = c;
    if (c == 0) t0++; else if (c == 1) t1++; else t2++;
  }
  sc[0][tid] = t0; sc[1][tid] = t1; sc[2][tid] = t2;
  __syncthreads();
  for (int d = 1; d < 256; d <<= 1) {
    int v0 = tid >= d ? sc[0][tid - d] : 0;
    int v1 = tid >= d ? sc[1][tid - d] : 0;
    int v2 = tid >= d ? sc[2][tid - d] : 0;
    __syncthreads();
    sc[0][tid] += v0; sc[1][tid] += v1; sc[2][tid] += v2;
    __syncthreads();
  }
  int q0 = sc[0][tid] - t0, q1 = sc[1][tid] - t1, q2 = sc[2][tid] - t2;
  int tc0 = sc[0][255], tc1 = sc[1][255], tc2 = sc[2][255];
  for (int j = 0; j < 8; j++) {
    int n = base + j; int c = tcl[j];
    if (c == 0) T0[q0++] = n;
    else if (c == 1) T1[q1++] = n;
    else T2[q2++] = n;
  }
  for (int i = tc0 + tid; i < NROWS; i += 256) T0[i] = 0;
  for (int i = tc1 + tid; i < NROWS; i += 256) T1[i] = 0;
  for (int i = tc2 + tid; i < NROWS; i += 256) T2[i] = 0;
  if (tid == 0) { counts[2] = tc0; counts[3] = tc1; counts[4] = tc2; }
}

// ---------------- fused pack / convert / transpose ----------------
constexpr int PB0 = HEADP;            // headw  (20224)
constexpr int PB1 = PB0 + VTP / 4;    // w1p    (+10048)
constexpr int PB2 = PB1 + VTP / 8;    // w2p    (+5024)
constexpr int PB3 = PB2 + 1024;       // ep0f
constexpr int PB4 = PB3 + 256;        // ep1f
constexpr int PB5 = PB4 + 64;         // ep2f
constexpr int PB6 = PB5 + 1024;       // op0T (32x32)
constexpr int PB7 = PB6 + 256;        // op1T (8x32)
constexpr int PB8 = PB7 + 128;        // op2T (4x32)

DEVI void cvt_f16(const float* src, _Float16* dst, int vb, int tid) {
  int g = vb * 256 + tid;
  float4 v = *(const float4*)(src + (size_t)g * 4);
  f16x4 o = {(_Float16)v.x, (_Float16)v.y, (_Float16)v.z, (_Float16)v.w};
  *(f16x4*)(dst + (size_t)g * 4) = o;
}

DEVI void tr32(const float* in, _Float16* out, int C, int bx, int by, int tid) {
  __shared__ float tile[32][33];
  int c0 = bx * 32, r0 = by * 32;
  int tx = tid & 31, ty = tid >> 5;          // (32, 8)
  for (int i = 0; i < 4; i++) {
    int c = c0 + tx; int r = r0 + ty + i * 8;
    tile[ty + i * 8][tx] = (c < C) ? in[(size_t)r * C + c] : 0.f;
  }
  __syncthreads();
  for (int i = 0; i < 4; i++)
    out[(size_t)(c0 + ty + i * 8) * 1024 + r0 + tx] = (_Float16)tile[tx][ty + i * 8];
}

__global__ void fused_pack(const float* __restrict__ out_w0, const float* __restrict__ out_b0,
                           const float* __restrict__ cluster_w, const float* __restrict__ cluster_b,
                           const float* __restrict__ out_w1, const float* __restrict__ out_b1,
                           const float* __restrict__ out_w2, const float* __restrict__ out_b2,
                           const float* __restrict__ emb_proj0, const float* __restrict__ emb_proj1,
                           const float* __restrict__ emb_proj2,
                           const float* __restrict__ out_proj0, const float* __restrict__ out_proj1,
                           const float* __restrict__ out_proj2,
                           _Float16* headw, float* headb,
                           _Float16* w1p, float* b1p, _Float16* w2p, float* b2p,
                           _Float16* ep0f, _Float16* ep1f, _Float16* ep2f,
                           _Float16* op0T, _Float16* op1T, _Float16* op2T)
{
  int bid = blockIdx.x, tid = threadIdx.x;
  if (bid < PB0) {
    int g = bid * 256 + tid;
    int r = g >> 8, k4 = (g & 255) << 2;
    float4 v = {0.f, 0.f, 0.f, 0.f};
    if (r < 20000)      v = *(const float4*)(out_w0 + ((size_t)r << 10) + k4);
    else if (r < 20002) v = *(const float4*)(cluster_w + ((size_t)(r - 20000) << 10) + k4);
    f16x4 o = {(_Float16)v.x, (_Float16)v.y, (_Float16)v.z, (_Float16)v.w};
    *(f16x4*)(headw + ((size_t)r << 10) + k4) = o;
    if (g < HEADP) headb[g] = g < 20000 ? out_b0[g] : (g < 20002 ? cluster_b[g - 20000] : -1e30f);
  } else if (bid < PB1) {
    int g = (bid - PB0) * 256 + tid;          // VTP*64
    int r = g >> 6, k4 = (g & 63) << 2;
    float4 v = {0.f, 0.f, 0.f, 0.f};
    if (r < VT) v = *(const float4*)(out_w1 + ((size_t)r << 8) + k4);
    f16x4 o = {(_Float16)v.x, (_Float16)v.y, (_Float16)v.z, (_Float16)v.w};
    *(f16x4*)(w1p + ((size_t)r << 8) + k4) = o;
    if (g < VTP) b1p[g] = g < VT ? out_b1[g] : -1e30f;
  } else if (bid < PB2) {
    int g = (bid - PB1) * 256 + tid;          // VTP*32 (Eout=128, Ein=64)
    int r = g >> 5, k4 = (g & 31) << 2;
    float4 v = {0.f, 0.f, 0.f, 0.f};
    if (r < VT && k4 < 64) v = *(const float4*)(out_w2 + ((size_t)r << 6) + k4);
    f16x4 o = {(_Float16)v.x, (_Float16)v.y, (_Float16)v.z, (_Float16)v.w};
    *(f16x4*)(w2p + ((size_t)r << 7) + k4) = o;
    if (g < VTP) b2p[g] = g < VT ? out_b2[g] : -1e30f;
  } else if (bid < PB3) { cvt_f16(emb_proj0, ep0f, bid - PB2, tid); }
  else if (bid < PB4) { cvt_f16(emb_proj1, ep1f, bid - PB3, tid); }
  else if (bid < PB5) { cvt_f16(emb_proj2, ep2f, bid - PB4, tid); }
  else if (bid < PB6) { int l = bid - PB5; tr32(out_proj0, op0T, 1024, l & 31, l >> 5, tid); }
  else if (bid < PB7) { int l = bid - PB6; tr32(out_proj1, op1T, 256, l & 7, l >> 3, tid); }
  else                { int l = bid - PB7; tr32(out_proj2, op2T, 64, l & 3, l >> 2, tid); }
}

// ---------------- fused gather ----------------
DEVI void gat(const float* emb, const int* x, const int* list, _Float16* dst,
              int tbase, int vmax, int log2E, int vb, int tid) {
  int g = vb * 256 + tid;
  int r = g >> (log2E - 2);
  int e4 = (g & ((1 << (log2E - 2)) - 1)) << 2;
  int n = list[r];
  int tl = x[n] - tbase;
  tl = tl < 0 ? 0 : (tl >= vmax ? vmax - 1 : tl);
  float4 v = *(const float4*)(emb + ((size_t)tl << log2E) + e4);
  f16x4 o = {(_Float16)(v.x * 32.f), (_Float16)(v.y * 32.f),
             (_Float16)(v.z * 32.f), (_Float16)(v.w * 32.f)};
  *(f16x4*)(dst + ((size_t)r << log2E) + e4) = o;
}

__global__ void fused_gather(const float* __restrict__ emb_w0, const float* __restrict__ emb_w1,
                             const float* __restrict__ emb_w2, const int* __restrict__ x,
                             const int* __restrict__ T0, const int* __restrict__ T1,
                             const int* __restrict__ T2,
                             _Float16* E0, _Float16* E1, _Float16* E2)
{
  int bid = blockIdx.x, tid = threadIdx.x;
  if (bid < 2048)      gat(emb_w0, x, T0, E0, 0, 20000, 10, bid, tid);
  else if (bid < 2560) gat(emb_w1, x, T1, E1, 20000, 40000, 8, bid - 2048, tid);
  else                 gat(emb_w2, x, T2, E2, 60000, 40000, 6, bid - 2560, tid);
}

// ---------------- 128-tile GEMM (for small hidden/proj stages) ----------------
__global__ __launch_bounds__(256)
void gemm128(const _Float16* __restrict__ A, int lda,
             const _Float16* __restrict__ Wm, int ldw,
             _Float16* __restrict__ C, int ldc, int Nvalid,
             const int* __restrict__ amap, const int* __restrict__ cmap,
             const int* __restrict__ cnt, int K)
{
  int rb = blockIdx.x, cb = blockIdx.y;
  int valid = cnt ? *cnt : NROWS;
  if (cnt && rb * 128 >= valid) return;
  __shared__ __attribute__((aligned(16))) _Float16 As[128 * 32];
  __shared__ __attribute__((aligned(16))) _Float16 Ws[128 * 32];
  int tid = threadIdx.x;
  int lane = tid & 63, wid = tid >> 6;
  int wr = wid >> 1, wc = wid & 1;
  int sr = wid * 32 + (lane >> 2);
  int arow0 = rb * 128 + sr, arow1 = arow0 + 16;
  if (amap) { arow0 = amap[arow0]; arow1 = amap[arow1]; }
  int ko = (lane & 3) * 8;
  const _Float16* ag0 = A + (size_t)arow0 * lda + ko;
  const _Float16* ag1 = A + (size_t)arow1 * lda + ko;
  const _Float16* wg0 = Wm + (size_t)(cb * 128 + sr) * ldw + ko;
  const _Float16* wg1 = wg0 + (size_t)16 * ldw;
  _Float16* as0 = As + (wid * 32) * 32;
  _Float16* as1 = as0 + 16 * 32;
  _Float16* ws0 = Ws + (wid * 32) * 32;
  _Float16* ws1 = ws0 + 16 * 32;
  f32x4 acc[4][4] = {};
  int lr = lane & 15, lk = (lane >> 4) * 8;
  const int nk = K >> 5;
  for (int kt = 0; kt < nk; ++kt) {
    int kofs = kt * 32;
    glds16(ag0 + kofs, as0);
    glds16(ag1 + kofs, as1);
    glds16(wg0 + kofs, ws0);
    glds16(wg1 + kofs, ws1);
    __syncthreads();
    f16x8 af[4], bf[4];
    #pragma unroll
    for (int mi = 0; mi < 4; mi++)
      af[mi] = *(const f16x8*)(As + (wr * 64 + mi * 16 + lr) * 32 + lk);
    #pragma unroll
    for (int ni = 0; ni < 4; ni++)
      bf[ni] = *(const f16x8*)(Ws + (wc * 64 + ni * 16 + lr) * 32 + lk);
    #pragma unroll
    for (int mi = 0; mi < 4; mi++)
      #pragma unroll
      for (int ni = 0; ni < 4; ni++)
        acc[mi][ni] = __builtin_amdgcn_mfma_f32_16x16x32_f16(af[mi], bf[ni], acc[mi][ni], 0, 0, 0);
    __syncthreads();
  }
  #pragma unroll
  for (int mi = 0; mi < 4; mi++) {
    #pragma unroll
    for (int j = 0; j < 4; j++) {
      int rl = wr * 64 + mi * 16 + (lane >> 4) * 4 + j;
      int rg = rb * 128 + rl;
      if (rg >= valid) continue;
      int orow = cmap ? cmap[rg] : rg;
      #pragma unroll
      for (int ni = 0; ni < 4; ni++) {
        int col = cb * 128 + wc * 64 + ni * 16 + (lane & 15);
        if (col < Nvalid) C[(size_t)orow * ldc + col] = (_Float16)acc[mi][ni][j];
      }
    }
  }
}

// ---------------- 256-tile 8-phase GEMM + online-LSE epilogue ----------------
DEVI void rdA8(f16x8 (&af)[8], const _Float16* p) {
  #pragma unroll
  for (int mi = 0; mi < 8; ++mi) af[mi] = *(const f16x8*)(p + mi * 512);
}
DEVI void rdB2(f16x8 (&bf)[2], const _Float16* p) {
  bf[0] = *(const f16x8*)(p);
  bf[1] = *(const f16x8*)(p + 512);
}
template<int NB>
DEVI void mma16(f32x4 (&acc)[8][4], const f16x8 (&af)[8], const f16x8 (&bf)[2]) {
  #pragma unroll
  for (int mi = 0; mi < 8; ++mi) {
    acc[mi][NB]     = __builtin_amdgcn_mfma_f32_16x16x32_f16(af[mi], bf[0], acc[mi][NB],     0, 0, 0);
    acc[mi][NB + 1] = __builtin_amdgcn_mfma_f32_16x16x32_f16(af[mi], bf[1], acc[mi][NB + 1], 0, 0, 0);
  }
}
DEVI void stg2(const _Float16* g0, const _Float16* g1, _Float16* l) {
  glds16(g0, l);
  glds16(g1, l + 4096);
}

__global__ __launch_bounds__(512, 1)
void gemm_lse(const _Float16* __restrict__ A, int lda,
              const _Float16* __restrict__ Wm, int ldw,
              const float* __restrict__ bias,
              const int* __restrict__ cnt,
              float* __restrict__ pm, float* __restrict__ ps,
              int pstride, int K, int nrb)
{
  __shared__ __attribute__((aligned(16))) _Float16 lds[65536];   // 128 KiB
  _Float16* lA = lds;
  _Float16* lB = lds + 32768;
  constexpr int H00 = 0, H01 = 8192, H10 = 16384, H11 = 24576;

  int bid = blockIdx.x;
  int qq = gridDim.x >> 3;                 // grid divisible by 8
  int w = (bid & 7) * qq + (bid >> 3);     // XCD-contiguous cb panels
  int rb = w % nrb, cb = w / nrb;
  int valid = cnt ? *cnt : NROWS;
  if (rb * 256 >= valid) return;

  int tid = threadIdx.x;
  int lane = tid & 63, wid = tid >> 6;
  int wr = wid >> 2, wc = wid & 3;
  int lr = lane & 15;

  // staging: thread covers 16B chunk q0 (round0) / q0+512 (round1); src pre-swizzled
  int q0 = wid * 64 + lane;
  int r0 = q0 >> 2;
  int scol = (((lane & 3) ^ ((q0 >> 3) & 3)) << 3);
  const _Float16* pA0 = A + (size_t)(rb * 256 + r0) * lda + scol;
  const _Float16* pA1 = pA0 + (size_t)128 * lda;
  const _Float16* pB0 = Wm + (size_t)(cb * 256 + r0) * ldw + scol;
  const _Float16* pB1 = pB0 + (size_t)128 * ldw;
  int sdA = wid * 512;

  // fragment read bases (swizzled slot)
  int slotf = (((lane >> 4) ^ ((lr >> 1) & 3)) << 3);
  int laneA = (wr * 128 + lr) * 32 + slotf;
  int laneB = (wc * 64 + lr) * 32 + slotf;

  f32x4 acc[8][4] = {};
  f16x8 af[8], bf[2];

  // reset counters (cnt read above), then prologue: stage halves 0..5
  asm volatile("s_waitcnt vmcnt(0) lgkmcnt(0)" ::: "memory");
  stg2(pA0,      pA1,      lA + H00 + sdA);   // t0 A ks0
  stg2(pB0,      pB1,      lB + H00 + sdA);   // t0 B ks0
  stg2(pA0 + 32, pA1 + 32, lA + H01 + sdA);   // t0 A ks1
  stg2(pB0 + 32, pB1 + 32, lB + H01 + sdA);   // t0 B ks1
  stg2(pA0 + 64, pA1 + 64, lA + H10 + sdA);   // t1 A ks0
  stg2(pB0 + 64, pB1 + 64, lB + H10 + sdA);   // t1 B ks0

  auto iter = [&](auto lastc, int koff) {
    constexpr bool LAST = decltype(lastc)::value;
    // p0: tile even, ks0, qn0
    VMW(8); BARX;
    rdA8(af, lA + H00 + laneA); rdB2(bf, lB + H00 + laneB);
    stg2(pA0 + koff + 96, pA1 + koff + 96, lA + H11 + sdA);     // t+1 A ks1
    PR1; mma16<0>(acc, af, bf); PR0;
    // p1: ks0, qn1
    BARX;
    rdB2(bf, lB + H00 + laneB + 1024);
    stg2(pB0 + koff + 96, pB1 + koff + 96, lB + H11 + sdA);     // t+1 B ks1
    PR1; mma16<2>(acc, af, bf); PR0;
    // p2: ks1, qn0
    VMW(8); BARX;
    rdA8(af, lA + H01 + laneA); rdB2(bf, lB + H01 + laneB);
    if constexpr (!LAST) stg2(pA0 + koff + 128, pA1 + koff + 128, lA + H00 + sdA);  // t+2 A ks0
    PR1; mma16<0>(acc, af, bf); PR0;
    // p3: ks1, qn1
    BARX;
    rdB2(bf, lB + H01 + laneB + 1024);
    if constexpr (!LAST) stg2(pB0 + koff + 128, pB1 + koff + 128, lB + H00 + sdA);
    PR1; mma16<2>(acc, af, bf); PR0;
    // p4: tile odd, ks0, qn0
    if constexpr (LAST) { VMW(4); } else { VMW(8); }
    BARX;
    rdA8(af, lA + H10 + laneA); rdB2(bf, lB + H10 + laneB);
    if constexpr (!LAST) stg2(pA0 + koff + 160, pA1 + koff + 160, lA + H01 + sdA);  // t+2 A ks1
    PR1; mma16<0>(acc, af, bf); PR0;
    // p5
    BARX;
    rdB2(bf, lB + H10 + laneB + 1024);
    if constexpr (!LAST) stg2(pB0 + koff + 160, pB1 + koff + 160, lB + H01 + sdA);
    PR1; mma16<2>(acc, af, bf); PR0;
    // p6: ks1, qn0
    if constexpr (LAST) { VMW(0); } else { VMW(8); }
    BARX;
    rdA8(af, lA + H11 + laneA); rdB2(bf, lB + H11 + laneB);
    if constexpr (!LAST) stg2(pA0 + koff + 192, pA1 + koff + 192, lA + H10 + sdA);  // t+3 A ks0
    PR1; mma16<0>(acc, af, bf); PR0;
    // p7
    BARX;
    rdB2(bf, lB + H11 + laneB + 1024);
    if constexpr (!LAST) stg2(pB0 + koff + 192, pB1 + koff + 192, lB + H10 + sdA);
    PR1; mma16<2>(acc, af, bf); PR0;
  };

  int nk = K >> 6;                         // K-tiles of 64, nk even, nk >= 2
  for (int kt2 = 0; kt2 + 2 < nk; kt2 += 2)
    iter(std::integral_constant<bool, false>{}, kt2 * 64);
  iter(std::integral_constant<bool, true>{}, (nk - 2) * 64);

  // ---- epilogue: per-row (max, sumexp) over this 256-col block ----
  float bv[4];
  #pragma unroll
  for (int u = 0; u < 4; ++u) bv[u] = bias[cb * 256 + wc * 64 + u * 16 + lr];
  float* lm = (float*)lds;                 // [4][256]
  float* lsm = lm + 1024;                  // [4][256]
  #pragma unroll
  for (int mi = 0; mi < 8; ++mi) {
    #pragma unroll
    for (int j = 0; j < 4; ++j) {
      float v0 = acc[mi][0][j] + bv[0], v1 = acc[mi][1][j] + bv[1];
      float v2 = acc[mi][2][j] + bv[2], v3 = acc[mi][3][j] + bv[3];
      float m = fmaxf(fmaxf(v0, v1), fmaxf(v2, v3));
      #pragma unroll
      for (int d = 1; d < 16; d <<= 1) m = fmaxf(m, __shfl_xor(m, d));
      float s = __expf(v0 - m) + __expf(v1 - m) + __expf(v2 - m) + __expf(v3 - m);
      #pragma unroll
      for (int d = 1; d < 16; d <<= 1) s += __shfl_xor(s, d);
      if (lr == 0) {
        int row = wr * 128 + mi * 16 + (lane >> 4) * 4 + j;
        lm[wc * 256 + row] = m; lsm[wc * 256 + row] = s;
      }
    }
  }
  __syncthreads();
  if (tid < 256) {
    float m0 = lm[tid], m1 = lm[256 + tid], m2 = lm[512 + tid], m3 = lm[768 + tid];
    float M = fmaxf(fmaxf(m0, m1), fmaxf(m2, m3));
    float S = lsm[tid] * __expf(m0 - M) + lsm[256 + tid] * __expf(m1 - M)
            + lsm[512 + tid] * __expf(m2 - M) + lsm[768 + tid] * __expf(m3 - M);
    int gr = rb * 256 + tid;
    pm[(size_t)gr * pstride + cb] = M;
    ps[(size_t)gr * pstride + cb] = S;
  }
}

// ---------------- finish: target logits + LSE reduce + NLL ----------------
DEVI float lsew(const float* m, const float* s, int nb, int lane) {
  float M = -3e38f;
  for (int i = lane; i < nb; i += 64) M = fmaxf(M, m[i]);
  #pragma unroll
  for (int d = 1; d < 64; d <<= 1) M = fmaxf(M, __shfl_xor(M, d));
  float S = 0.f;
  for (int i = lane; i < nb; i += 64) S += s[i] * __expf(m[i] - M);
  #pragma unroll
  for (int d = 1; d < 64; d <<= 1) S += __shfl_xor(S, d);
  return M + __logf(S);
}

__global__ void finish_kernel(const _Float16* __restrict__ ph0, const _Float16* __restrict__ headw,
                              const float* __restrict__ headb,
                              const _Float16* __restrict__ ph1c, const _Float16* __restrict__ w1p,
                              const float* __restrict__ b1p,
                              const _Float16* __restrict__ ph2c, const _Float16* __restrict__ w2p,
                              const float* __restrict__ b2p,
                              const int* __restrict__ headcol, const int* __restrict__ tailpos,
                              const int* __restrict__ pos1, const int* __restrict__ pos2,
                              const int* __restrict__ cl,
                              const float* __restrict__ pmh, const float* __restrict__ psh,
                              const float* __restrict__ pm1, const float* __restrict__ ps1,
                              const float* __restrict__ pm2, const float* __restrict__ ps2,
                              float* __restrict__ out)
{
  int n = blockIdx.x;
  int tid = threadIdx.x, lane = tid & 63, wid = tid >> 6;
  __shared__ float sh[6];
  int c = cl[n];
  if (wid == 0) {
    int hc = headcol[n];
    const f16x8* a = (const f16x8*)(ph0 + (size_t)n * 1024 + lane * 16);
    const f16x8* ww = (const f16x8*)(headw + (size_t)hc * 1024 + lane * 16);
    float s = 0.f;
    #pragma unroll
    for (int u = 0; u < 2; u++) {
      f16x8 av = a[u], wv = ww[u];
      #pragma unroll
      for (int j = 0; j < 8; j++) s += (float)av[j] * (float)wv[j];
    }
    #pragma unroll
    for (int d = 1; d < 64; d <<= 1) s += __shfl_xor(s, d);
    if (lane == 0) sh[0] = s + headb[hc];
  } else if (wid == 1 && c == 1) {
    int p = pos1[n], t = tailpos[n];
    f16x4 av = *(const f16x4*)(ph1c + (size_t)p * 256 + lane * 4);
    f16x4 wv = *(const f16x4*)(w1p + (size_t)t * 256 + lane * 4);
    float s = (float)av[0] * (float)wv[0] + (float)av[1] * (float)wv[1]
            + (float)av[2] * (float)wv[2] + (float)av[3] * (float)wv[3];
    #pragma unroll
    for (int d = 1; d < 64; d <<= 1) s += __shfl_xor(s, d);
    float l = lsew(pm1 + (size_t)p * PSTT, ps1 + (size_t)p * PSTT, NCBT, lane);
    if (lane == 0) { sh[1] = s + b1p[t]; sh[4] = l; }
  } else if (wid == 2 && c == 2) {
    int p = pos2[n], t = tailpos[n];
    const _Float16* a = ph2c + (size_t)p * 128 + lane * 2;
    const _Float16* ww = w2p + (size_t)t * 128 + lane * 2;
    float s = (float)a[0] * (float)ww[0] + (float)a[1] * (float)ww[1];
    #pragma unroll
    for (int d = 1; d < 64; d <<= 1) s += __shfl_xor(s, d);
    float l = lsew(pm2 + (size_t)p * PSTT, ps2 + (size_t)p * PSTT, NCBT, lane);
    if (lane == 0) { sh[2] = s + b2p[t]; sh[5] = l; }
  } else if (wid == 3) {
    float l = lsew(pmh + (size_t)n * PSTH, psh + (size_t)n * PSTH, NCBH, lane);
    if (lane == 0) sh[3] = l;
  }
  __syncthreads();
  if (tid == 0) {
    float nll = sh[3] - sh[0];
    if (c == 1)      nll += sh[4] - sh[1];
    else if (c == 2) nll += sh[5] - sh[2];
    out[n] = nll;
  }
}

// ---------------- driver ----------------
extern "C" void kernel_launch(void* const* d_in, const int* in_sizes, int n_in,
                              void* d_out, int out_size, void* d_ws, size_t ws_size,
                              hipStream_t stream)
{
  const int*   x         = (const int*)d_in[0];
  const int*   labels    = (const int*)d_in[1];
  const float* emb_w0    = (const float*)d_in[2];
  const float* emb_w1    = (const float*)d_in[3];
  const float* emb_w2    = (const float*)d_in[4];
  const float* emb_proj0 = (const float*)d_in[5];
  const float* emb_proj1 = (const float*)d_in[6];
  const float* emb_proj2 = (const float*)d_in[7];
  const float* out_w0    = (const float*)d_in[8];
  const float* out_b0    = (const float*)d_in[9];
  const float* out_w1    = (const float*)d_in[10];
  const float* out_b1    = (const float*)d_in[11];
  const float* out_w2    = (const float*)d_in[12];
  const float* out_b2    = (const float*)d_in[13];
  const float* out_proj0 = (const float*)d_in[14];
  const float* out_proj1 = (const float*)d_in[15];
  const float* out_proj2 = (const float*)d_in[16];
  const float* cluster_w = (const float*)d_in[17];
  const float* cluster_b = (const float*)d_in[18];
  float* out = (float*)d_out;

  char* ws = (char*)d_ws;
  size_t off = 0;
  auto alloc = [&](size_t bytes) -> void* {
    void* p = ws + off;
    off = (off + bytes + 255) & ~(size_t)255;
    return p;
  };
  _Float16* headw = (_Float16*)alloc((size_t)HEADP * 1024 * 2);
  float*    headb = (float*)alloc((size_t)HEADP * 4);
  _Float16* w1p   = (_Float16*)alloc((size_t)VTP * 256 * 2);
  float*    b1p   = (float*)alloc((size_t)VTP * 4);
  _Float16* w2p   = (_Float16*)alloc((size_t)VTP * 128 * 2);
  float*    b2p   = (float*)alloc((size_t)VTP * 4);
  _Float16* ep0f  = (_Float16*)alloc((size_t)1024 * 1024 * 2);
  _Float16* ep1f  = (_Float16*)alloc((size_t)1024 * 256 * 2);
  _Float16* ep2f  = (_Float16*)alloc((size_t)1024 * 64 * 2);
  _Float16* op0T  = (_Float16*)alloc((size_t)1024 * 1024 * 2);
  _Float16* op1T  = (_Float16*)alloc((size_t)256 * 1024 * 2);
  _Float16* op2T  = (_Float16*)alloc((size_t)128 * 1024 * 2);
  _Float16* E0    = (_Float16*)alloc((size_t)NROWS * 1024 * 2);
  _Float16* E1    = (_Float16*)alloc((size_t)NROWS * 256 * 2);
  _Float16* E2    = (_Float16*)alloc((size_t)NROWS * 64 * 2);
  _Float16* hid   = (_Float16*)alloc((size_t)NROWS * 1024 * 2);
  _Float16* ph0   = (_Float16*)alloc((size_t)NROWS * 1024 * 2);
  _Float16* ph1c  = (_Float16*)alloc((size_t)NROWS * 256 * 2);
  _Float16* ph2c  = (_Float16*)alloc((size_t)NROWS * 128 * 2);
  float* pmh = (float*)alloc((size_t)NROWS * PSTH * 4);
  float* psh = (float*)alloc((size_t)NROWS * PSTH * 4);
  float* pm1 = (float*)alloc((size_t)NROWS * PSTT * 4);
  float* ps1 = (float*)alloc((size_t)NROWS * PSTT * 4);
  float* pm2 = (float*)alloc((size_t)NROWS * PSTT * 4);
  float* ps2 = (float*)alloc((size_t)NROWS * PSTT * 4);
  int* L1 = (int*)alloc(NROWS * 4);
  int* L2 = (int*)alloc(NROWS * 4);
  int* T0 = (int*)alloc(NROWS * 4);
  int* T1 = (int*)alloc(NROWS * 4);
  int* T2 = (int*)alloc(NROWS * 4);
  int* counts  = (int*)alloc(16 * 4);
  int* cl      = (int*)alloc(NROWS * 4);
  int* headcol = (int*)alloc(NROWS * 4);
  int* tailpos = (int*)alloc(NROWS * 4);
  int* pos1    = (int*)alloc(NROWS * 4);
  int* pos2    = (int*)alloc(NROWS * 4);
  (void)ws_size; (void)in_sizes; (void)n_in; (void)out_size;

  prep_kernel<<<1, 256, 0, stream>>>(x, labels, cl, headcol, tailpos, pos1, pos2,
                                     L1, L2, T0, T1, T2, counts);

  fused_pack<<<PB8, 256, 0, stream>>>(out_w0, out_b0, cluster_w, cluster_b,
                                      out_w1, out_b1, out_w2, out_b2,
                                      emb_proj0, emb_proj1, emb_proj2,
                                      out_proj0, out_proj1, out_proj2,
                                      headw, headb, w1p, b1p, w2p, b2p,
                                      ep0f, ep1f, ep2f, op0T, op1T, op2T);

  fused_gather<<<2688, 256, 0, stream>>>(emb_w0, emb_w1, emb_w2, x, T0, T1, T2, E0, E1, E2);

  // hidden per token cluster (scatter via T-lists)
  gemm128<<<dim3(16, 8), 256, 0, stream>>>(E0, 1024, ep0f, 1024, hid, 1024, 1024,
                                           nullptr, T0, counts + 2, 1024);
  gemm128<<<dim3(16, 8), 256, 0, stream>>>(E1, 256, ep1f, 256, hid, 1024, 1024,
                                           nullptr, T1, counts + 3, 256);
  gemm128<<<dim3(16, 8), 256, 0, stream>>>(E2, 64, ep2f, 64, hid, 1024, 1024,
                                           nullptr, T2, counts + 4, 64);

  // projections
  gemm128<<<dim3(16, 8), 256, 0, stream>>>(hid, 1024, op0T, 1024, ph0, 1024, 1024,
                                           nullptr, nullptr, nullptr, 1024);
  gemm128<<<dim3(16, 2), 256, 0, stream>>>(hid, 1024, op1T, 1024, ph1c, 256, 256,
                                           L1, nullptr, counts + 0, 1024);
  gemm128<<<dim3(16, 1), 256, 0, stream>>>(hid, 1024, op2T, 1024, ph2c, 128, 128,
                                           L2, nullptr, counts + 1, 1024);

  // logits + online-LSE partials (256-tile 8-phase)
  gemm_lse<<<8 * NCBH, 512, 0, stream>>>(ph0, 1024, headw, 1024, headb, nullptr,
                                         pmh, psh, PSTH, 1024, 8);
  gemm_lse<<<8 * NCBT, 512, 0, stream>>>(ph1c, 256, w1p, 256, b1p, counts + 0,
                                         pm1, ps1, PSTT, 256, 8);
  gemm_lse<<<8 * NCBT, 512, 0, stream>>>(ph2c, 128, w2p, 128, b2p, counts + 1,
                                         pm2, ps2, PSTT, 128, 8);

  finish_kernel<<<NROWS, 256, 0, stream>>>(ph0, headw, headb, ph1c, w1p, b1p,
                                           ph2c, w2p, b2p, headcol, tailpos, pos1, pos2, cl,
                                           pmh, psh, pm1, ps1, pm2, ps2, out);
}